// Round 6
// baseline (257.667 us; speedup 1.0000x reference)
//
#include <hip/hip_runtime.h>
#include <math.h>

#define C_CLASSES 32000
#define C4 8000                 // float4 per row
#define BLOCK 512
#define NWAVES 8
#define FULL_ITERS 15           // 15*512 = 7680 float4
#define TAIL_N 320              // 8000 - 7680
#define CAP 2048                // candidate capacity (expect ~1000 w/ per-wave thr)

__device__ __forceinline__ float wave_sum(float x){
  #pragma unroll
  for (int m = 32; m >= 1; m >>= 1) x += __shfl_xor(x, m, 64);
  return x;
}
__device__ __forceinline__ float wave_max(float x){
  #pragma unroll
  for (int m = 32; m >= 1; m >>= 1) x = fmaxf(x, __shfl_xor(x, m, 64));
  return x;
}

__global__ __launch_bounds__(BLOCK) void sparsemax_fused_kernel(
    const float* __restrict__ input,
    const float* __restrict__ target,
    const float* __restrict__ weight,
    float* __restrict__ rowloss)
{
  __shared__ float s_val[CAP];      // candidate raw x values
  __shared__ int   s_idx[CAP];      // candidate class indices (for weight)
  __shared__ float sA[NWAVES], sBd[NWAVES], sW[NWAVES], sM[NWAVES];
  __shared__ float s_bc;            // Michelot broadcast (fallback)
  __shared__ float s_m, s_base, s_sw;
  __shared__ int   s_cnt;
  __shared__ int   s_flag;

  const int row  = blockIdx.x;
  const int tid  = threadIdx.x;
  const int lane = tid & 63;
  const int wid  = tid >> 6;

  const float4* in4 = (const float4*)(input  + (size_t)row * C_CLASSES);
  const float4* tg4 = (const float4*)(target + (size_t)row * C_CLASSES);
  const float4* wt4 = (const float4*)weight;

  // ---- init shared counter BEFORE any global loads: barrier has no vmem
  // to drain, so it costs only the wave sync. ----
  if (tid == 0){ s_cnt = 0; s_flag = 0; }
  __syncthreads();

  // ---- per-wave conservative threshold: no cross-wave sync needed.
  // Any subset max <= rowmax, so thr_w = (wave's first-256-elem max) - 1
  // satisfies {x > thr_w} superset of the active set {x > rowmax - 1}
  // (tau* in [-1,0) after the max shift). ----
  float4 v0 = in4[tid];
  float lm = fmaxf(fmaxf(v0.x, v0.y), fmaxf(v0.z, v0.w));
  const float thr = wave_max(lm) - 1.0f;   // per-wave, register-only

  // ---- single streaming pass, barrier-free ----
  // elementwise: w*(0.5 z^2 + 0.5 t^2 - t z) = 0.5 w (z-t)^2,  z = x - m
  //   => row base = 0.5*sum(w d^2) - m*sum(w d) + 0.5 m^2 sum(w),  d = x - t
  float A2 = 0.0f, Bd = 0.0f, Sw = 0.0f, rm = lm;

#define PROC(xc, tc, wc, gidx)                                               \
  {                                                                          \
    float x = (xc), w = (wc);                                                \
    float d = x - (tc);                                                      \
    float wd = w * d;                                                        \
    A2 += wd * d;  Bd += wd;  Sw += w;                                       \
    if (x > thr){                                                            \
      int p = atomicAdd(&s_cnt, 1);                                          \
      if (p < CAP){ s_val[p] = x; s_idx[p] = (gidx); }                       \
    }                                                                        \
  }

  {
    float4 t4 = tg4[tid]; float4 w4 = wt4[tid];
    const int gi = tid * 4;
    PROC(v0.x, t4.x, w4.x, gi + 0)
    PROC(v0.y, t4.y, w4.y, gi + 1)
    PROC(v0.z, t4.z, w4.z, gi + 2)
    PROC(v0.w, t4.w, w4.w, gi + 3)
  }
  #pragma unroll 2
  for (int j = 1; j < FULL_ITERS; ++j){
    const int i = tid + j * BLOCK;
    float4 v = in4[i]; float4 t4 = tg4[i]; float4 w4 = wt4[i];
    rm = fmaxf(rm, fmaxf(fmaxf(v.x, v.y), fmaxf(v.z, v.w)));
    const int gi = i * 4;
    PROC(v.x, t4.x, w4.x, gi + 0)
    PROC(v.y, t4.y, w4.y, gi + 1)
    PROC(v.z, t4.z, w4.z, gi + 2)
    PROC(v.w, t4.w, w4.w, gi + 3)
  }
  if (tid < TAIL_N){
    const int i = FULL_ITERS * BLOCK + tid;
    float4 v = in4[i]; float4 t4 = tg4[i]; float4 w4 = wt4[i];
    rm = fmaxf(rm, fmaxf(fmaxf(v.x, v.y), fmaxf(v.z, v.w)));
    const int gi = i * 4;
    PROC(v.x, t4.x, w4.x, gi + 0)
    PROC(v.y, t4.y, w4.y, gi + 1)
    PROC(v.z, t4.z, w4.z, gi + 2)
    PROC(v.w, t4.w, w4.w, gi + 3)
  }
#undef PROC

  // ---- block reductions ----
  rm = wave_max(rm);
  A2 = wave_sum(A2); Bd = wave_sum(Bd); Sw = wave_sum(Sw);
  if (lane == 0){ sM[wid] = rm; sA[wid] = A2; sBd[wid] = Bd; sW[wid] = Sw; }
  __syncthreads();
  if (tid == 0){
    float m8 = sM[0], A8 = sA[0], Bd8 = sBd[0], Sw8 = sW[0];
    #pragma unroll
    for (int w = 1; w < NWAVES; ++w){
      m8 = fmaxf(m8, sM[w]); A8 += sA[w]; Bd8 += sBd[w]; Sw8 += sW[w];
    }
    s_m    = m8;
    s_base = 0.5f * A8 - m8 * Bd8 + 0.5f * m8 * m8 * Sw8;
    s_sw   = Sw8;
  }
  __syncthreads();
  const float m    = s_m;
  const float base = s_base;
  const float sw8  = s_sw;
  const int   cnt  = s_cnt;

  if (cnt <= CAP){
    // ---- wave-0 Michelot on candidates ----
    if (wid == 0){
      float t = -1.0f;
      for (int it = 0; it < 200; ++it){
        float s = 0.0f, k = 0.0f;
        for (int i = lane; i < cnt; i += 64){
          float z = s_val[i] - m;
          if (z > t){ s += z; k += 1.0f; }
        }
        s = wave_sum(s); k = wave_sum(k);
        float tn = (s - 1.0f) / k;        // k>=1: the max element (z=0) always > t
        if (!(tn > t)) break;             // monotone from below -> exact fixpoint
        t = tn;
      }
      const float t2 = t * t;
      float corr = 0.0f;
      for (int i = lane; i < cnt; i += 64){
        float z = s_val[i] - m;
        if (z > t) corr += weight[s_idx[i]] * (z * z - t2);
      }
      corr = wave_sum(corr);
      if (lane == 0)
        rowloss[row] = base - 0.5f * t2 * sw8 - 0.5f * corr;
    }
  } else {
    // ---- fallback: block-wide Michelot over global row (L3-resident) ----
    const float* inf = input + (size_t)row * C_CLASSES;
    float t = -1.0f;
    for (int it = 0; it < 200; ++it){
      float s = 0.0f, k = 0.0f;
      for (int i = tid; i < C_CLASSES; i += BLOCK){
        float z = inf[i] - m;
        if (z > t){ s += z; k += 1.0f; }
      }
      s = wave_sum(s); k = wave_sum(k);
      if (lane == 0){ sA[wid] = s; sBd[wid] = k; }
      __syncthreads();
      if (tid == 0){
        float S = 0.0f, K = 0.0f;
        for (int w = 0; w < NWAVES; ++w){ S += sA[w]; K += sBd[w]; }
        float tn = (S - 1.0f) / K;
        if (!(tn > t)) s_flag = 1; else s_bc = tn;
      }
      __syncthreads();
      if (s_flag) break;    // uniform
      t = s_bc;
    }
    const float t2 = t * t;
    float corr = 0.0f;
    for (int i = tid; i < C_CLASSES; i += BLOCK){
      float z = inf[i] - m;
      if (z > t) corr += weight[i] * (z * z - t2);
    }
    corr = wave_sum(corr);
    if (lane == 0) sA[wid] = corr;
    __syncthreads();
    if (tid == 0){
      float C8 = 0.0f;
      for (int w = 0; w < NWAVES; ++w) C8 += sA[w];
      rowloss[row] = base - 0.5f * t2 * sw8 - 0.5f * C8;
    }
  }
}

__global__ __launch_bounds__(1024) void reduce_mean_kernel(
    const float* __restrict__ rowloss, float* __restrict__ out, int B)
{
  __shared__ float s_red[16];
  const int tid  = threadIdx.x;
  const int lane = tid & 63;
  const int wid  = tid >> 6;
  float acc = 0.0f;
  for (int i = tid; i < B; i += 1024) acc += rowloss[i];
  acc = wave_sum(acc);
  if (lane == 0) s_red[wid] = acc;
  __syncthreads();
  if (tid < 64){
    float x = (lane < 16) ? s_red[lane] : 0.0f;
    x = wave_sum(x);
    if (lane == 0) out[0] = x / (float)B;
  }
}

extern "C" void kernel_launch(void* const* d_in, const int* in_sizes, int n_in,
                              void* d_out, int out_size, void* d_ws, size_t ws_size,
                              hipStream_t stream)
{
  const float* input  = (const float*)d_in[0];
  const float* target = (const float*)d_in[1];
  const float* weight = (const float*)d_in[2];
  float* out     = (float*)d_out;
  float* rowloss = (float*)d_ws;

  const int C = in_sizes[2];           // 32000
  const int B = in_sizes[0] / C;       // 4096

  sparsemax_fused_kernel<<<B, BLOCK, 0, stream>>>(input, target, weight, rowloss);
  reduce_mean_kernel<<<1, 1024, 0, stream>>>(rowloss, out, B);
}

// Round 7
// 187.943 us; speedup vs baseline: 1.3710x; 1.3710x over previous
//
#include <hip/hip_runtime.h>
#include <math.h>

#define C_CLASSES 32000
#define C4 8000                 // float4 per row
#define BLOCK 512
#define NWAVES 8
#define FULL_ITERS 15           // 15*512 = 7680 float4
#define TAIL_N 320              // 8000 - 7680
#define CAP 2048                // candidate capacity (expect ~390)
#define THR 2.25f               // static candidate threshold; validity checked
                                // post-stream against true rowmax (fallback if
                                // THR > m-1), so correctness is data-independent.

__device__ __forceinline__ float wave_sum(float x){
  #pragma unroll
  for (int m = 32; m >= 1; m >>= 1) x += __shfl_xor(x, m, 64);
  return x;
}
__device__ __forceinline__ float wave_max(float x){
  #pragma unroll
  for (int m = 32; m >= 1; m >>= 1) x = fmaxf(x, __shfl_xor(x, m, 64));
  return x;
}

__global__ __launch_bounds__(BLOCK) void sparsemax_fused_kernel(
    const float* __restrict__ input,
    const float* __restrict__ target,
    const float* __restrict__ weight,
    float* __restrict__ rowloss)
{
  __shared__ float s_val[CAP];      // candidate raw x values
  __shared__ int   s_idx[CAP];      // candidate class indices (for weight)
  __shared__ float sA[NWAVES], sBd[NWAVES], sW[NWAVES], sM[NWAVES];
  __shared__ float s_bc;            // Michelot broadcast (fallback)
  __shared__ float s_m, s_base, s_sw;
  __shared__ int   s_cnt;
  __shared__ int   s_flag;

  const int row  = blockIdx.x;
  const int tid  = threadIdx.x;
  const int lane = tid & 63;
  const int wid  = tid >> 6;

  const float4* in4 = (const float4*)(input  + (size_t)row * C_CLASSES);
  const float4* tg4 = (const float4*)(target + (size_t)row * C_CLASSES);
  const float4* wt4 = (const float4*)weight;

  // init shared counter BEFORE any global loads (barrier drains nothing)
  if (tid == 0){ s_cnt = 0; s_flag = 0; }
  __syncthreads();

  const float thr = THR;

  // ---- single streaming pass, no seed phase ----
  // elementwise: w*(0.5 z^2 + 0.5 t^2 - t z) = 0.5 w (z-t)^2,  z = x - m
  //   => row base = 0.5*sum(w d^2) - m*sum(w d) + 0.5 m^2 sum(w),  d = x - t
  float A2 = 0.0f, Bd = 0.0f, Sw = 0.0f, rm = -3.0e38f;

#define PROC(xc, tc, wc, gidx)                                               \
  {                                                                          \
    float x = (xc), w = (wc);                                                \
    float d = x - (tc);                                                      \
    float wd = w * d;                                                        \
    A2 += wd * d;  Bd += wd;  Sw += w;                                       \
    if (x > thr){                                                            \
      int p = atomicAdd(&s_cnt, 1);                                          \
      if (p < CAP){ s_val[p] = x; s_idx[p] = (gidx); }                       \
    }                                                                        \
  }

  #pragma unroll 2
  for (int j = 0; j < FULL_ITERS; ++j){
    const int i = tid + j * BLOCK;
    float4 v = in4[i]; float4 t4 = tg4[i]; float4 w4 = wt4[i];
    rm = fmaxf(rm, fmaxf(fmaxf(v.x, v.y), fmaxf(v.z, v.w)));
    const int gi = i * 4;
    PROC(v.x, t4.x, w4.x, gi + 0)
    PROC(v.y, t4.y, w4.y, gi + 1)
    PROC(v.z, t4.z, w4.z, gi + 2)
    PROC(v.w, t4.w, w4.w, gi + 3)
  }
  if (tid < TAIL_N){
    const int i = FULL_ITERS * BLOCK + tid;
    float4 v = in4[i]; float4 t4 = tg4[i]; float4 w4 = wt4[i];
    rm = fmaxf(rm, fmaxf(fmaxf(v.x, v.y), fmaxf(v.z, v.w)));
    const int gi = i * 4;
    PROC(v.x, t4.x, w4.x, gi + 0)
    PROC(v.y, t4.y, w4.y, gi + 1)
    PROC(v.z, t4.z, w4.z, gi + 2)
    PROC(v.w, t4.w, w4.w, gi + 3)
  }
#undef PROC

  // ---- block reductions ----
  rm = wave_max(rm);
  A2 = wave_sum(A2); Bd = wave_sum(Bd); Sw = wave_sum(Sw);
  if (lane == 0){ sM[wid] = rm; sA[wid] = A2; sBd[wid] = Bd; sW[wid] = Sw; }
  __syncthreads();
  if (tid == 0){
    float m8 = sM[0], A8 = sA[0], Bd8 = sBd[0], Sw8 = sW[0];
    #pragma unroll
    for (int w = 1; w < NWAVES; ++w){
      m8 = fmaxf(m8, sM[w]); A8 += sA[w]; Bd8 += sBd[w]; Sw8 += sW[w];
    }
    s_m    = m8;
    s_base = 0.5f * A8 - m8 * Bd8 + 0.5f * m8 * m8 * Sw8;
    s_sw   = Sw8;
  }
  __syncthreads();
  const float m    = s_m;
  const float base = s_base;
  const float sw8  = s_sw;
  const int   cnt  = s_cnt;

  // candidate path valid iff {x>THR} is a superset of the active set
  // {x > m-1} (i.e. THR <= m-1) and the buffer didn't overflow.
  if (cnt <= CAP && thr <= m - 1.0f){
    // ---- wave-0 Michelot on candidates ----
    if (wid == 0){
      float t = -1.0f;
      for (int it = 0; it < 200; ++it){
        float s = 0.0f, k = 0.0f;
        for (int i = lane; i < cnt; i += 64){
          float z = s_val[i] - m;
          if (z > t){ s += z; k += 1.0f; }
        }
        s = wave_sum(s); k = wave_sum(k);
        float tn = (s - 1.0f) / k;        // k>=1: the max element (z=0) always > t
        if (!(tn > t)) break;             // monotone from below -> exact fixpoint
        t = tn;
      }
      const float t2 = t * t;
      float corr = 0.0f;
      for (int i = lane; i < cnt; i += 64){
        float z = s_val[i] - m;
        if (z > t) corr += weight[s_idx[i]] * (z * z - t2);
      }
      corr = wave_sum(corr);
      if (lane == 0)
        rowloss[row] = base - 0.5f * t2 * sw8 - 0.5f * corr;
    }
  } else {
    // ---- fallback: block-wide Michelot over global row (L3-resident) ----
    const float* inf = input + (size_t)row * C_CLASSES;
    float t = -1.0f;
    for (int it = 0; it < 200; ++it){
      float s = 0.0f, k = 0.0f;
      for (int i = tid; i < C_CLASSES; i += BLOCK){
        float z = inf[i] - m;
        if (z > t){ s += z; k += 1.0f; }
      }
      s = wave_sum(s); k = wave_sum(k);
      if (lane == 0){ sA[wid] = s; sBd[wid] = k; }
      __syncthreads();
      if (tid == 0){
        float S = 0.0f, K = 0.0f;
        for (int w = 0; w < NWAVES; ++w){ S += sA[w]; K += sBd[w]; }
        float tn = (S - 1.0f) / K;
        if (!(tn > t)) s_flag = 1; else s_bc = tn;
      }
      __syncthreads();
      if (s_flag) break;    // uniform
      t = s_bc;
    }
    const float t2 = t * t;
    float corr = 0.0f;
    for (int i = tid; i < C_CLASSES; i += BLOCK){
      float z = inf[i] - m;
      if (z > t) corr += weight[i] * (z * z - t2);
    }
    corr = wave_sum(corr);
    if (lane == 0) sA[wid] = corr;
    __syncthreads();
    if (tid == 0){
      float C8 = 0.0f;
      for (int w = 0; w < NWAVES; ++w) C8 += sA[w];
      rowloss[row] = base - 0.5f * t2 * sw8 - 0.5f * C8;
    }
  }
}

__global__ __launch_bounds__(1024) void reduce_mean_kernel(
    const float* __restrict__ rowloss, float* __restrict__ out, int B)
{
  __shared__ float s_red[16];
  const int tid  = threadIdx.x;
  const int lane = tid & 63;
  const int wid  = tid >> 6;
  float acc = 0.0f;
  for (int i = tid; i < B; i += 1024) acc += rowloss[i];
  acc = wave_sum(acc);
  if (lane == 0) s_red[wid] = acc;
  __syncthreads();
  if (tid < 64){
    float x = (lane < 16) ? s_red[lane] : 0.0f;
    x = wave_sum(x);
    if (lane == 0) out[0] = x / (float)B;
  }
}

extern "C" void kernel_launch(void* const* d_in, const int* in_sizes, int n_in,
                              void* d_out, int out_size, void* d_ws, size_t ws_size,
                              hipStream_t stream)
{
  const float* input  = (const float*)d_in[0];
  const float* target = (const float*)d_in[1];
  const float* weight = (const float*)d_in[2];
  float* out     = (float*)d_out;
  float* rowloss = (float*)d_ws;

  const int C = in_sizes[2];           // 32000
  const int B = in_sizes[0] / C;       // 4096

  sparsemax_fused_kernel<<<B, BLOCK, 0, stream>>>(input, target, weight, rowloss);
  reduce_mean_kernel<<<1, 1024, 0, stream>>>(rowloss, out, B);
}